// Round 1
// baseline (504.052 us; speedup 1.0000x reference)
//
#include <hip/hip_runtime.h>

#define B_ 8
#define S_ 1024
#define D_ 1024
#define H_ 16
#define DK_ 64
#define M_ (B_ * S_)
#define NEGINF -1e38f

typedef __bf16 bf16_t;
typedef __bf16 bf16x8 __attribute__((ext_vector_type(8)));
typedef float f32x4 __attribute__((ext_vector_type(4)));
typedef unsigned int u32;

__device__ inline f32x4 mfma_bf16(bf16x8 a, bf16x8 b, f32x4 c) {
    return __builtin_amdgcn_mfma_f32_16x16x32_bf16(a, b, c, 0, 0, 0);
}

// Async global->LDS, 16B per lane. LDS dest = (wave-uniform base) + lane*16B.
typedef const __attribute__((address_space(1))) u32* gas1_t;
typedef __attribute__((address_space(3))) u32* las3_t;
__device__ inline void gl_lds16(const void* g, void* l) {
    __builtin_amdgcn_global_load_lds((gas1_t)g, (las3_t)l, 16, 0, 0);
}

// 8 contiguous elements -> bf16x8 (converting when source is fp32).
__device__ inline bf16x8 load8(const bf16_t* p) { return *(const bf16x8*)p; }
__device__ inline bf16x8 load8(const float* p) {
    const f32x4 a = *(const f32x4*)p;
    const f32x4 b = *(const f32x4*)(p + 4);
    bf16x8 r;
    r[0] = (bf16_t)a[0]; r[1] = (bf16_t)a[1];
    r[2] = (bf16_t)a[2]; r[3] = (bf16_t)a[3];
    r[4] = (bf16_t)b[0]; r[5] = (bf16_t)b[1];
    r[6] = (bf16_t)b[2]; r[7] = (bf16_t)b[3];
    return r;
}
__device__ inline void store_elem(bf16_t* Y, size_t i, float v) { Y[i] = (bf16_t)v; }
__device__ inline void store_elem(float* Y, size_t i, float v) { Y[i] = v; }

// ---------------------------------------------------------------------------
// Transpose+convert 4 fp32 weight matrices [1024,1024] -> bf16 transposed.
// ---------------------------------------------------------------------------
__global__ __launch_bounds__(256) void transpose4(
    const float* __restrict__ i0, const float* __restrict__ i1,
    const float* __restrict__ i2, const float* __restrict__ i3,
    bf16_t* __restrict__ o0, bf16_t* __restrict__ o1,
    bf16_t* __restrict__ o2, bf16_t* __restrict__ o3) {
    const float* ins[4] = {i0, i1, i2, i3};
    bf16_t* outs[4] = {o0, o1, o2, o3};
    const float* in = ins[blockIdx.z];
    bf16_t* out = outs[blockIdx.z];
    __shared__ __align__(16) bf16_t t[32][33];
    const int n0 = blockIdx.x * 32, k0 = blockIdx.y * 32;
    const int tx = threadIdx.x;
    for (int i = threadIdx.y; i < 32; i += 8)
        t[i][tx] = (bf16_t)in[(size_t)(k0 + i) * D_ + n0 + tx];
    __syncthreads();
    for (int i = threadIdx.y; i < 32; i += 8)
        out[(size_t)(n0 + i) * D_ + k0 + tx] = t[tx][i];
}

// ---------------------------------------------------------------------------
// C[M,N] = X[M,K] * Wt[N,K]^T + bias, K=N=1024, M=8192. bf16 MFMA, fp32 acc.
// B tile staged via global_load_lds (16B); A tile likewise when X is bf16,
// else fp32 vector-load + in-register bf16 convert.
// MODE 0: Y fp32 row-major [M,N];  MODE 1: bf16 [B,H,S,DK];  MODE 2: bf16
// [B,H,DK,S]. Block: 4 waves, tile 128x128, BK=32, wave = 64x64 (4x4 MFMA).
// ---------------------------------------------------------------------------
template <int MODE, typename TX, typename TY>
__global__ __launch_bounds__(256) void gemm_bt(
    const TX* __restrict__ X, const bf16_t* __restrict__ Wt,
    const float* __restrict__ bias, TY* __restrict__ Y, float scale) {
    __shared__ __align__(16) bf16_t As[128 * 32];
    __shared__ __align__(16) bf16_t Bs[128 * 32];
    const int tid = threadIdx.x;
    const int lane = tid & 63, wave = tid >> 6;
    const int ln = lane & 15, quad = lane >> 4;
    const int wm = (wave & 1) * 64, wn = (wave >> 1) * 64;
    const int m0 = blockIdx.x * 128, n0 = blockIdx.y * 128;

    const int srow = tid >> 2, scc = (tid & 3) * 8;
    const TX* pa0 = X + (size_t)(m0 + srow) * D_ + scc;
    const TX* pa1 = pa0 + (size_t)64 * D_;
    const bf16_t* pb0 = Wt + (size_t)(n0 + srow) * D_ + scc;
    const bf16_t* pb1 = pb0 + (size_t)64 * D_;
    bf16_t* qa0 = As + srow * 32 + scc;
    bf16_t* qa1 = As + (srow + 64) * 32 + scc;

    f32x4 acc[4][4] = {};
    for (int k0 = 0; k0 < D_; k0 += 32) {
        if constexpr (sizeof(TX) == 2) {
            gl_lds16(pa0 + k0, As + wave * 512);
            gl_lds16(pa1 + k0, As + 2048 + wave * 512);
        } else {
            *(bf16x8*)qa0 = load8(pa0 + k0);
            *(bf16x8*)qa1 = load8(pa1 + k0);
        }
        gl_lds16(pb0 + k0, Bs + wave * 512);
        gl_lds16(pb1 + k0, Bs + 2048 + wave * 512);
        __syncthreads();
        bf16x8 af[4], bfr[4];
#pragma unroll
        for (int mt = 0; mt < 4; mt++)
            af[mt] = *(const bf16x8*)(As + (wm + mt * 16 + ln) * 32 + quad * 8);
#pragma unroll
        for (int nt = 0; nt < 4; nt++)
            bfr[nt] = *(const bf16x8*)(Bs + (wn + nt * 16 + ln) * 32 + quad * 8);
#pragma unroll
        for (int mt = 0; mt < 4; mt++)
#pragma unroll
            for (int nt = 0; nt < 4; nt++)
                acc[mt][nt] = mfma_bf16(af[mt], bfr[nt], acc[mt][nt]);
        __syncthreads();
    }

#pragma unroll
    for (int mt = 0; mt < 4; mt++) {
#pragma unroll
        for (int nt = 0; nt < 4; nt++) {
#pragma unroll
            for (int r = 0; r < 4; r++) {
                const int m = m0 + wm + mt * 16 + quad * 4 + r;
                const int n = n0 + wn + nt * 16 + ln;
                const float v = (acc[mt][nt][r] + bias[n]) * scale;
                size_t idx;
                if (MODE == 0) {
                    idx = (size_t)m * D_ + n;
                } else {
                    const int b = m >> 10, s = m & 1023;
                    const int h = n >> 6, d = n & 63;
                    if (MODE == 1)
                        idx = ((size_t)(b * H_ + h) * S_ + s) * DK_ + d;
                    else
                        idx = ((size_t)(b * H_ + h) * DK_ + d) * S_ + s;
                }
                store_elem(Y, idx, v);
            }
        }
    }
}

// ---------------------------------------------------------------------------
// Causal flash attention, FIXED-max exp2-domain softmax, ZERO-barrier tiles.
// Q pre-scaled by log2e/sqrt(DK); p = exp2(score - 16), with the -16 shift
// folded into the QK^T accumulator init (free). Softmax is shift-invariant
// so the fixed shift is exact; |score| < 16 with astronomic margin.
// K/V per (b,h) is 256 KB -> L2-resident. We do NOT stage K/V in LDS:
// fragments are read directly from global (16B contiguous per lane, L2-hit).
// This removes both per-tile __syncthreads() and the staging loop entirely;
// the only LDS use is the per-wave P transpose buffer (intra-wave lgkmcnt
// ordering, no block barrier). Row-sum li via MFMA with a ones-fragment.
// Grid: (8 q-chunks, B*H). One 128-row q-chunk per block, heavy chunks
// (j near 7) dispatched first for tail balance. 4 independent waves/block.
// Q,K: [B*H,S,DK]  Vt: [B*H,DK,S]  ctx: [B,S,D] bf16.
// ---------------------------------------------------------------------------
__global__ __launch_bounds__(256, 2) void MaskedMultiHeadAttention_90709709291709_kernel(
    const bf16_t* __restrict__ Q, const bf16_t* __restrict__ K,
    const bf16_t* __restrict__ Vt, bf16_t* __restrict__ ctx) {
    __shared__ __align__(16) bf16_t pbuf[4][32 * 64];

    const int bh = blockIdx.y;
    const int j = 7 - (int)blockIdx.x;  // heavy-first dispatch order
    const int tid = threadIdx.x;
    const int lane = tid & 63, wave = tid >> 6;
    const int ln = lane & 15, quad = lane >> 4;

    const bf16_t* Qb = Q + (size_t)bh * S_ * DK_;
    const bf16_t* Kb = K + (size_t)bh * S_ * DK_;
    const bf16_t* Vb = Vt + (size_t)bh * DK_ * S_;
    const int b = bh >> 4, h = bh & 15;

    bf16x8 ones8;
#pragma unroll
    for (int i = 0; i < 8; i++) ones8[i] = (bf16_t)1.0f;

    const int qb = j * 128;
    const int wq = qb + wave * 32;
    bf16_t* pb = pbuf[wave];

    bf16x8 qf[2][2];
#pragma unroll
    for (int mi = 0; mi < 2; mi++)
#pragma unroll
        for (int kk = 0; kk < 2; kk++)
            qf[mi][kk] = *(const bf16x8*)(
                Qb + (size_t)(wq + mi * 16 + ln) * DK_ + kk * 32 + quad * 8);

    f32x4 o[2][4] = {};
    f32x4 ol[2] = {};

    const int kend = qb + 128;
    for (int kt = 0; kt < kend; kt += 64) {
        const bool act0 = kt <= wq + 15;
        const bool act1 = kt <= wq + 31;
        if (!act1) continue;  // no barriers -> divergence across waves is fine

        // -------- QK^T + masked exp2 -> pbuf (per-wave, swizzled) --------
#pragma unroll
        for (int mi = 0; mi < 2; mi++) {
            if (!(mi ? act1 : act0)) continue;
            f32x4 s[4];
#pragma unroll
            for (int nt = 0; nt < 4; nt++) {
                f32x4 a = {-16.f, -16.f, -16.f, -16.f};  // exp2-domain shift
#pragma unroll
                for (int kk = 0; kk < 2; kk++) {
                    const bf16x8 kf = *(const bf16x8*)(
                        Kb + (size_t)(kt + nt * 16 + ln) * DK_ + kk * 32 +
                        quad * 8);
                    a = mfma_bf16(qf[mi][kk], kf, a);
                }
                s[nt] = a;
            }
            const bool needmask = (kt + 63) > (wq + mi * 16);
#pragma unroll
            for (int r = 0; r < 4; r++) {
                const int row = wq + mi * 16 + quad * 4 + r;
                const int prow = mi * 16 + quad * 4 + r;
#pragma unroll
                for (int nt = 0; nt < 4; nt++) {
                    float v = s[nt][r];
                    if (needmask && (kt + nt * 16 + ln > row)) v = NEGINF;
                    const float p = __builtin_amdgcn_exp2f(v);
                    const int col = nt * 16 + ln;
                    pb[prow * 64 + (((col >> 3) ^ (prow & 7)) * 8) +
                       (col & 7)] = (bf16_t)p;
                }
            }
        }

        // -------- P * V (V fragments straight from global/L2) --------
        // intra-wave LDS write->read: compiler emits lgkmcnt wait;
        // no block barrier needed (pbuf is per-wave).
#pragma unroll
        for (int mi = 0; mi < 2; mi++) {
            if (!(mi ? act1 : act0)) continue;
            bf16x8 pf[2];
#pragma unroll
            for (int kk = 0; kk < 2; kk++)
                pf[kk] = *(const bf16x8*)(
                    pb + (mi * 16 + ln) * 64 + (((kk * 4 + quad) ^ (ln & 7)) * 8));
#pragma unroll
            for (int kk = 0; kk < 2; kk++)
                ol[mi] = mfma_bf16(pf[kk], ones8, ol[mi]);
#pragma unroll
            for (int dk = 0; dk < 4; dk++)
#pragma unroll
                for (int kk = 0; kk < 2; kk++) {
                    const bf16x8 vf = *(const bf16x8*)(
                        Vb + (size_t)(dk * 16 + ln) * S_ + kt + kk * 32 +
                        quad * 8);
                    o[mi][dk] = mfma_bf16(pf[kk], vf, o[mi][dk]);
                }
        }
    }

#pragma unroll
    for (int mi = 0; mi < 2; mi++)
#pragma unroll
        for (int r = 0; r < 4; r++) {
            const float inv = 1.f / ol[mi][r];
            const int row = wq + mi * 16 + quad * 4 + r;
            const size_t base = ((size_t)b * S_ + row) * D_ + h * DK_;
#pragma unroll
            for (int dk = 0; dk < 4; dk++)
                ctx[base + dk * 16 + ln] = (bf16_t)(o[mi][dk][r] * inv);
        }
}

// Vectorized d2d copy (16B per thread).
__global__ __launch_bounds__(256) void copy16(const f32x4* __restrict__ src,
                                              f32x4* __restrict__ dst, int n4) {
    const int i = blockIdx.x * 256 + threadIdx.x;
    if (i < n4) dst[i] = src[i];
}

extern "C" void kernel_launch(void* const* d_in, const int* in_sizes, int n_in,
                              void* d_out, int out_size, void* d_ws,
                              size_t ws_size, hipStream_t stream) {
    const float* query = (const float*)d_in[0];
    const float* key = (const float*)d_in[1];
    const float* value = (const float*)d_in[2];
    const float* w_q = (const float*)d_in[4];
    const float* b_q = (const float*)d_in[5];
    const float* w_k = (const float*)d_in[6];
    const float* b_k = (const float*)d_in[7];
    const float* w_v = (const float*)d_in[8];
    const float* b_v = (const float*)d_in[9];
    const float* w_o = (const float*)d_in[10];
    const float* b_o = (const float*)d_in[11];

    bf16_t* ws = (bf16_t*)d_ws;
    const size_t M8 = (size_t)M_ * D_;  // 8M elems
    bf16_t* Qw = ws;                    // [0, 8M)
    bf16_t* Kw = ws + M8;               // [8M, 16M)
    bf16_t* Vw = ws + 2 * M8;           // [16M, 24M)
    bf16_t* wtq = ws + 3 * M8;          // [24M, 28M): 4 x 1M
    bf16_t* wtk = wtq + (size_t)D_ * D_;
    bf16_t* wtv = wtk + (size_t)D_ * D_;
    bf16_t* wto = wtv + (size_t)D_ * D_;

    // If ws is big enough (>= 72 MB), park ctx in ws and write the final
    // fp32 output GEMM directly into d_out -> no copy pass. Otherwise fall
    // back to the proven ctx-in-d_out + copy scheme (56 MB footprint).
    const size_t need_direct = (4 * M8 + 4 * (size_t)D_ * D_) * sizeof(bf16_t);
    const bool direct = ws_size >= need_direct;
    bf16_t* Cw = direct ? (ws + 3 * M8 + 4 * (size_t)D_ * D_)
                        : (bf16_t*)d_out;
    float* Yw = direct ? (float*)d_out : (float*)ws;

    transpose4<<<dim3(32, 32, 4), dim3(32, 8, 1), 0, stream>>>(
        w_q, w_k, w_v, w_o, wtq, wtk, wtv, wto);

    const dim3 gg(M_ / 128, D_ / 128, 1);
    // Q scale folds 1/sqrt(DK) AND log2(e) for the exp2-domain softmax.
    const float qscale = 0.125f * 1.4426950408889634f;
    gemm_bt<1><<<gg, 256, 0, stream>>>(query, wtq, b_q, Qw, qscale);
    gemm_bt<1><<<gg, 256, 0, stream>>>(key, wtk, b_k, Kw, 1.0f);
    gemm_bt<2><<<gg, 256, 0, stream>>>(value, wtv, b_v, Vw, 1.0f);

    MaskedMultiHeadAttention_90709709291709_kernel<<<dim3(8, B_ * H_, 1), 256,
                                                     0, stream>>>(Qw, Kw, Vw,
                                                                  Cw);

    gemm_bt<0><<<gg, 256, 0, stream>>>(Cw, wto, b_o, Yw, 1.0f);
    if (!direct) {
        const int n4 = (int)((M8 * 4) / 16);
        copy16<<<dim3((n4 + 255) / 256), 256, 0, stream>>>((const f32x4*)Yw,
                                                           (f32x4*)d_out, n4);
    }
}

// Round 2
// 377.248 us; speedup vs baseline: 1.3361x; 1.3361x over previous
//
#include <hip/hip_runtime.h>

#define B_ 8
#define S_ 1024
#define D_ 1024
#define H_ 16
#define DK_ 64
#define M_ (B_ * S_)
#define NEGINF -1e38f

typedef __bf16 bf16_t;
typedef __bf16 bf16x8 __attribute__((ext_vector_type(8)));
typedef float f32x4 __attribute__((ext_vector_type(4)));
typedef unsigned int u32;

__device__ inline f32x4 mfma_bf16(bf16x8 a, bf16x8 b, f32x4 c) {
    return __builtin_amdgcn_mfma_f32_16x16x32_bf16(a, b, c, 0, 0, 0);
}

// Async global->LDS, 16B per lane. LDS dest = (wave-uniform base) + lane*16B.
typedef const __attribute__((address_space(1))) u32* gas1_t;
typedef __attribute__((address_space(3))) u32* las3_t;
__device__ inline void gl_lds16(const void* g, void* l) {
    __builtin_amdgcn_global_load_lds((gas1_t)g, (las3_t)l, 16, 0, 0);
}

// 8 contiguous elements -> bf16x8 (converting when source is fp32).
__device__ inline bf16x8 load8(const bf16_t* p) { return *(const bf16x8*)p; }
__device__ inline bf16x8 load8(const float* p) {
    const f32x4 a = *(const f32x4*)p;
    const f32x4 b = *(const f32x4*)(p + 4);
    bf16x8 r;
    r[0] = (bf16_t)a[0]; r[1] = (bf16_t)a[1];
    r[2] = (bf16_t)a[2]; r[3] = (bf16_t)a[3];
    r[4] = (bf16_t)b[0]; r[5] = (bf16_t)b[1];
    r[6] = (bf16_t)b[2]; r[7] = (bf16_t)b[3];
    return r;
}
__device__ inline void store_elem(bf16_t* Y, size_t i, float v) { Y[i] = (bf16_t)v; }
__device__ inline void store_elem(float* Y, size_t i, float v) { Y[i] = v; }

// ---------------------------------------------------------------------------
// Transpose+convert 4 fp32 weight matrices [1024,1024] -> bf16 transposed.
// ---------------------------------------------------------------------------
__global__ __launch_bounds__(256) void transpose4(
    const float* __restrict__ i0, const float* __restrict__ i1,
    const float* __restrict__ i2, const float* __restrict__ i3,
    bf16_t* __restrict__ o0, bf16_t* __restrict__ o1,
    bf16_t* __restrict__ o2, bf16_t* __restrict__ o3) {
    const float* ins[4] = {i0, i1, i2, i3};
    bf16_t* outs[4] = {o0, o1, o2, o3};
    const float* in = ins[blockIdx.z];
    bf16_t* out = outs[blockIdx.z];
    __shared__ __align__(16) bf16_t t[32][33];
    const int n0 = blockIdx.x * 32, k0 = blockIdx.y * 32;
    const int tx = threadIdx.x;
    for (int i = threadIdx.y; i < 32; i += 8)
        t[i][tx] = (bf16_t)in[(size_t)(k0 + i) * D_ + n0 + tx];
    __syncthreads();
    for (int i = threadIdx.y; i < 32; i += 8)
        out[(size_t)(n0 + i) * D_ + k0 + tx] = t[tx][i];
}

// ---------------------------------------------------------------------------
// C[M,N] = X[M,K] * Wt[N,K]^T + bias, K=N=1024, M=8192. bf16 MFMA, fp32 acc.
// BK=64 (16 K-iters, halved barrier count vs BK=32). LDS chunk XOR-swizzle:
// LDS[row][slot s] holds global chunk s ^ (row&7) -> ds_read_b128 fragment
// reads are 2-way (free) instead of ~8/16-way bank-conflicted. The swizzle
// is applied on the GLOBAL source address (guide rule #21): global_load_lds
// destination stays linear (base + lane*16B).
// Grid (N/128, M/128): blocks sharing an n-panel have linear ids = x (mod 8)
// -> same XCD -> the 2MB B-panel stays in that XCD's L2.
// MODE 0: Y fp32 row-major [M,N];  MODE 1: bf16 [B,H,S,DK];  MODE 2: bf16
// [B,H,DK,S]. Block: 4 waves, tile 128x128, wave = 64x64 (4x4 MFMA).
// ---------------------------------------------------------------------------
template <int MODE, typename TX, typename TY>
__global__ __launch_bounds__(256) void gemm_bt(
    const TX* __restrict__ X, const bf16_t* __restrict__ Wt,
    const float* __restrict__ bias, TY* __restrict__ Y, float scale) {
    __shared__ __align__(16) bf16_t As[128 * 64];
    __shared__ __align__(16) bf16_t Bs[128 * 64];
    const int tid = threadIdx.x;
    const int lane = tid & 63, wave = tid >> 6;
    const int ln = lane & 15, quad = lane >> 4;
    const int wm = (wave & 1) * 64, wn = (wave >> 1) * 64;
    const int n0 = blockIdx.x * 128, m0 = blockIdx.y * 128;

    const int srow = tid >> 3;         // 0..31
    const int sch = tid & 7;           // LDS slot this thread fills
    const int swc = sch ^ (srow & 7);  // global chunk that belongs in slot sch

    const TX* pa = X + (size_t)(m0 + srow) * D_ + swc * 8;
    const bf16_t* pb = Wt + (size_t)(n0 + srow) * D_ + swc * 8;

    f32x4 acc[4][4] = {};
    for (int k0 = 0; k0 < D_; k0 += 64) {
        if constexpr (sizeof(TX) == 2) {
#pragma unroll
            for (int i = 0; i < 4; i++)
                gl_lds16(pa + (size_t)(i * 32) * D_ + k0,
                         As + i * 2048 + wave * 512);
        } else {
#pragma unroll
            for (int i = 0; i < 4; i++)
                *(bf16x8*)(As + (srow + i * 32) * 64 + sch * 8) =
                    load8(X + (size_t)(m0 + srow + i * 32) * D_ + k0 + swc * 8);
        }
#pragma unroll
        for (int i = 0; i < 4; i++)
            gl_lds16(pb + (size_t)(i * 32) * D_ + k0,
                     Bs + i * 2048 + wave * 512);
        __syncthreads();
#pragma unroll
        for (int kq = 0; kq < 2; kq++) {
            bf16x8 af[4], bfr[4];
            const int slot = ((kq * 4 + quad) ^ (ln & 7)) * 8;
#pragma unroll
            for (int mt = 0; mt < 4; mt++)
                af[mt] = *(const bf16x8*)(As + (wm + mt * 16 + ln) * 64 + slot);
#pragma unroll
            for (int nt = 0; nt < 4; nt++)
                bfr[nt] = *(const bf16x8*)(Bs + (wn + nt * 16 + ln) * 64 + slot);
#pragma unroll
            for (int mt = 0; mt < 4; mt++)
#pragma unroll
                for (int nt = 0; nt < 4; nt++)
                    acc[mt][nt] = mfma_bf16(af[mt], bfr[nt], acc[mt][nt]);
        }
        __syncthreads();
    }

#pragma unroll
    for (int mt = 0; mt < 4; mt++) {
#pragma unroll
        for (int nt = 0; nt < 4; nt++) {
#pragma unroll
            for (int r = 0; r < 4; r++) {
                const int m = m0 + wm + mt * 16 + quad * 4 + r;
                const int n = n0 + wn + nt * 16 + ln;
                const float v = (acc[mt][nt][r] + bias[n]) * scale;
                size_t idx;
                if (MODE == 0) {
                    idx = (size_t)m * D_ + n;
                } else {
                    const int b = m >> 10, s = m & 1023;
                    const int h = n >> 6, d = n & 63;
                    if (MODE == 1)
                        idx = ((size_t)(b * H_ + h) * S_ + s) * DK_ + d;
                    else
                        idx = ((size_t)(b * H_ + h) * DK_ + d) * S_ + s;
                }
                store_elem(Y, idx, v);
            }
        }
    }
}

// ---------------------------------------------------------------------------
// Causal flash attention, FIXED-max exp2-domain softmax, ZERO-barrier tiles.
// Q pre-scaled by log2e/sqrt(DK); p = exp2(score - 16), shift folded into the
// MFMA accumulator init. K/V fragments read straight from global (per-head
// K/V = 256 KB, L2-resident). Latency regime fixes vs r1:
//  - launch_bounds(256,4): all 1024 blocks resident (4 blocks/CU), 4x TLP.
//  - grid (bh, chunk): same-bh blocks have ids = bh (mod 8) -> same XCD ->
//    K/V served from one L2 instead of refetched by 8 XCDs.
//  - K/V fragment loads hoisted out of the mi loop (mi-invariant, was 2x).
//  - act0 special-casing dropped: NEGINF masking already yields exact 0s.
// Only LDS use: per-wave P transpose buffer (intra-wave lgkmcnt ordering,
// no block barrier). Row-sum via MFMA with a ones-fragment.
// Q,K: [B*H,S,DK]  Vt: [B*H,DK,S]  ctx: [B,S,D] bf16.
// ---------------------------------------------------------------------------
__global__ __launch_bounds__(256, 4) void MaskedMultiHeadAttention_90709709291709_kernel(
    const bf16_t* __restrict__ Q, const bf16_t* __restrict__ K,
    const bf16_t* __restrict__ Vt, bf16_t* __restrict__ ctx) {
    __shared__ __align__(16) bf16_t pbuf[4][32 * 64];

    const int bh = blockIdx.x;
    const int j = 7 - (int)blockIdx.y;  // heavy chunks dispatched first
    const int tid = threadIdx.x;
    const int lane = tid & 63, wave = tid >> 6;
    const int ln = lane & 15, quad = lane >> 4;

    const bf16_t* Qb = Q + (size_t)bh * S_ * DK_;
    const bf16_t* Kb = K + (size_t)bh * S_ * DK_;
    const bf16_t* Vb = Vt + (size_t)bh * DK_ * S_;
    const int b = bh >> 4, h = bh & 15;

    bf16x8 ones8;
#pragma unroll
    for (int i = 0; i < 8; i++) ones8[i] = (bf16_t)1.0f;

    const int qb = j * 128;
    const int wq = qb + wave * 32;
    bf16_t* pb = pbuf[wave];

    bf16x8 qf[2][2];
#pragma unroll
    for (int mi = 0; mi < 2; mi++)
#pragma unroll
        for (int kk = 0; kk < 2; kk++)
            qf[mi][kk] = *(const bf16x8*)(
                Qb + (size_t)(wq + mi * 16 + ln) * DK_ + kk * 32 + quad * 8);

    f32x4 o[2][4] = {};
    f32x4 ol[2] = {};

    const int kend = qb + 128;
    for (int kt = 0; kt < kend; kt += 64) {
        if (kt > wq + 31) continue;  // wave-divergent only; no barriers

        // -------- QK^T + masked exp2 -> pbuf (per-wave, swizzled) --------
#pragma unroll
        for (int nt = 0; nt < 4; nt++) {
            const bf16_t* kp = Kb + (size_t)(kt + nt * 16 + ln) * DK_ + quad * 8;
            const bf16x8 kf0 = *(const bf16x8*)kp;
            const bf16x8 kf1 = *(const bf16x8*)(kp + 32);
#pragma unroll
            for (int mi = 0; mi < 2; mi++) {
                f32x4 a = {-16.f, -16.f, -16.f, -16.f};  // exp2-domain shift
                a = mfma_bf16(qf[mi][0], kf0, a);
                a = mfma_bf16(qf[mi][1], kf1, a);
                const bool needmask = (kt + 63) > (wq + mi * 16);
#pragma unroll
                for (int r = 0; r < 4; r++) {
                    const int row = wq + mi * 16 + quad * 4 + r;
                    const int prow = mi * 16 + quad * 4 + r;
                    float v = a[r];
                    if (needmask && (kt + nt * 16 + ln > row)) v = NEGINF;
                    const float p = __builtin_amdgcn_exp2f(v);
                    const int col = nt * 16 + ln;
                    pb[prow * 64 + (((col >> 3) ^ (prow & 7)) * 8) +
                       (col & 7)] = (bf16_t)p;
                }
            }
        }

        // -------- P * V (V fragments straight from global/L2) --------
        // intra-wave LDS write->read: compiler emits lgkmcnt wait; pbuf is
        // per-wave so no block barrier is needed.
        bf16x8 pf[2][2];
#pragma unroll
        for (int mi = 0; mi < 2; mi++)
#pragma unroll
            for (int kk = 0; kk < 2; kk++)
                pf[mi][kk] = *(const bf16x8*)(
                    pb + (mi * 16 + ln) * 64 + (((kk * 4 + quad) ^ (ln & 7)) * 8));
#pragma unroll
        for (int mi = 0; mi < 2; mi++) {
            ol[mi] = mfma_bf16(pf[mi][0], ones8, ol[mi]);
            ol[mi] = mfma_bf16(pf[mi][1], ones8, ol[mi]);
        }
#pragma unroll
        for (int dk = 0; dk < 4; dk++) {
            const bf16_t* vp = Vb + (size_t)(dk * 16 + ln) * S_ + kt + quad * 8;
            const bf16x8 vf0 = *(const bf16x8*)vp;
            const bf16x8 vf1 = *(const bf16x8*)(vp + 32);
#pragma unroll
            for (int mi = 0; mi < 2; mi++) {
                o[mi][dk] = mfma_bf16(pf[mi][0], vf0, o[mi][dk]);
                o[mi][dk] = mfma_bf16(pf[mi][1], vf1, o[mi][dk]);
            }
        }
    }

#pragma unroll
    for (int mi = 0; mi < 2; mi++)
#pragma unroll
        for (int r = 0; r < 4; r++) {
            const float inv = 1.f / ol[mi][r];
            const int row = wq + mi * 16 + quad * 4 + r;
            const size_t base = ((size_t)b * S_ + row) * D_ + h * DK_;
#pragma unroll
            for (int dk = 0; dk < 4; dk++)
                ctx[base + dk * 16 + ln] = (bf16_t)(o[mi][dk][r] * inv);
        }
}

// Vectorized d2d copy (16B per thread).
__global__ __launch_bounds__(256) void copy16(const f32x4* __restrict__ src,
                                              f32x4* __restrict__ dst, int n4) {
    const int i = blockIdx.x * 256 + threadIdx.x;
    if (i < n4) dst[i] = src[i];
}

extern "C" void kernel_launch(void* const* d_in, const int* in_sizes, int n_in,
                              void* d_out, int out_size, void* d_ws,
                              size_t ws_size, hipStream_t stream) {
    const float* query = (const float*)d_in[0];
    const float* key = (const float*)d_in[1];
    const float* value = (const float*)d_in[2];
    const float* w_q = (const float*)d_in[4];
    const float* b_q = (const float*)d_in[5];
    const float* w_k = (const float*)d_in[6];
    const float* b_k = (const float*)d_in[7];
    const float* w_v = (const float*)d_in[8];
    const float* b_v = (const float*)d_in[9];
    const float* w_o = (const float*)d_in[10];
    const float* b_o = (const float*)d_in[11];

    bf16_t* ws = (bf16_t*)d_ws;
    const size_t M8 = (size_t)M_ * D_;  // 8M elems
    bf16_t* Qw = ws;                    // [0, 8M)
    bf16_t* Kw = ws + M8;               // [8M, 16M)
    bf16_t* Vw = ws + 2 * M8;           // [16M, 24M)
    bf16_t* wtq = ws + 3 * M8;          // [24M, 28M): 4 x 1M
    bf16_t* wtk = wtq + (size_t)D_ * D_;
    bf16_t* wtv = wtk + (size_t)D_ * D_;
    bf16_t* wto = wtv + (size_t)D_ * D_;

    // If ws is big enough (>= 72 MB), park ctx in ws and write the final
    // fp32 output GEMM directly into d_out -> no copy pass. Otherwise fall
    // back to the ctx-in-d_out + copy scheme (56 MB footprint).
    const size_t need_direct = (4 * M8 + 4 * (size_t)D_ * D_) * sizeof(bf16_t);
    const bool direct = ws_size >= need_direct;
    bf16_t* Cw = direct ? (ws + 3 * M8 + 4 * (size_t)D_ * D_)
                        : (bf16_t*)d_out;
    float* Yw = direct ? (float*)d_out : (float*)ws;

    transpose4<<<dim3(32, 32, 4), dim3(32, 8, 1), 0, stream>>>(
        w_q, w_k, w_v, w_o, wtq, wtk, wtv, wto);

    const dim3 gg(D_ / 128, M_ / 128, 1);  // (n-panel, m-panel): n-panel -> XCD
    // Q scale folds 1/sqrt(DK) AND log2(e) for the exp2-domain softmax.
    const float qscale = 0.125f * 1.4426950408889634f;
    gemm_bt<1><<<gg, 256, 0, stream>>>(query, wtq, b_q, Qw, qscale);
    gemm_bt<1><<<gg, 256, 0, stream>>>(key, wtk, b_k, Kw, 1.0f);
    gemm_bt<2><<<gg, 256, 0, stream>>>(value, wtv, b_v, Vw, 1.0f);

    MaskedMultiHeadAttention_90709709291709_kernel<<<dim3(B_ * H_, 8, 1), 256,
                                                     0, stream>>>(Qw, Kw, Vw,
                                                                  Cw);

    gemm_bt<0><<<gg, 256, 0, stream>>>(Cw, wto, b_o, Yw, 1.0f);
    if (!direct) {
        const int n4 = (int)((M8 * 4) / 16);
        copy16<<<dim3((n4 + 255) / 256), 256, 0, stream>>>((const f32x4*)Yw,
                                                           (f32x4*)d_out, n4);
    }
}

// Round 3
// 327.950 us; speedup vs baseline: 1.5370x; 1.1503x over previous
//
#include <hip/hip_runtime.h>

#define B_ 8
#define S_ 1024
#define D_ 1024
#define H_ 16
#define DK_ 64
#define M_ (B_ * S_)
#define NEGINF -1e38f

typedef __bf16 bf16_t;
typedef __bf16 bf16x8 __attribute__((ext_vector_type(8)));
typedef float f32x4 __attribute__((ext_vector_type(4)));
typedef unsigned int u32;

__device__ inline f32x4 mfma_bf16(bf16x8 a, bf16x8 b, f32x4 c) {
    return __builtin_amdgcn_mfma_f32_16x16x32_bf16(a, b, c, 0, 0, 0);
}

// Async global->LDS, 16B per lane. LDS dest = (wave-uniform base) + lane*16B.
typedef const __attribute__((address_space(1))) u32* gas1_t;
typedef __attribute__((address_space(3))) u32* las3_t;
__device__ inline void gl_lds16(const void* g, void* l) {
    __builtin_amdgcn_global_load_lds((gas1_t)g, (las3_t)l, 16, 0, 0);
}

// 8 contiguous elements -> bf16x8 (converting when source is fp32).
__device__ inline bf16x8 load8(const bf16_t* p) { return *(const bf16x8*)p; }
__device__ inline bf16x8 load8(const float* p) {
    const f32x4 a = *(const f32x4*)p;
    const f32x4 b = *(const f32x4*)(p + 4);
    bf16x8 r;
    r[0] = (bf16_t)a[0]; r[1] = (bf16_t)a[1];
    r[2] = (bf16_t)a[2]; r[3] = (bf16_t)a[3];
    r[4] = (bf16_t)b[0]; r[5] = (bf16_t)b[1];
    r[6] = (bf16_t)b[2]; r[7] = (bf16_t)b[3];
    return r;
}
__device__ inline void store_elem(bf16_t* Y, size_t i, float v) { Y[i] = (bf16_t)v; }
__device__ inline void store_elem(float* Y, size_t i, float v) { Y[i] = v; }

// ---------------------------------------------------------------------------
// Transpose+convert 4 fp32 weight matrices [1024,1024] -> bf16 transposed.
// ---------------------------------------------------------------------------
__global__ __launch_bounds__(256) void transpose4(
    const float* __restrict__ i0, const float* __restrict__ i1,
    const float* __restrict__ i2, const float* __restrict__ i3,
    bf16_t* __restrict__ o0, bf16_t* __restrict__ o1,
    bf16_t* __restrict__ o2, bf16_t* __restrict__ o3) {
    const float* ins[4] = {i0, i1, i2, i3};
    bf16_t* outs[4] = {o0, o1, o2, o3};
    const float* in = ins[blockIdx.z];
    bf16_t* out = outs[blockIdx.z];
    __shared__ __align__(16) bf16_t t[32][33];
    const int n0 = blockIdx.x * 32, k0 = blockIdx.y * 32;
    const int tx = threadIdx.x;
    for (int i = threadIdx.y; i < 32; i += 8)
        t[i][tx] = (bf16_t)in[(size_t)(k0 + i) * D_ + n0 + tx];
    __syncthreads();
    for (int i = threadIdx.y; i < 32; i += 8)
        out[(size_t)(n0 + i) * D_ + k0 + tx] = t[tx][i];
}

// fp32 -> bf16 bulk convert, 8 elems/thread (16B loads, 16B stores).
__global__ __launch_bounds__(256) void cvt_bf16(const float* __restrict__ in,
                                                bf16_t* __restrict__ out,
                                                int n8) {
    const int i = blockIdx.x * 256 + threadIdx.x;
    if (i < n8) *(bf16x8*)(out + (size_t)i * 8) = load8(in + (size_t)i * 8);
}

// ---------------------------------------------------------------------------
// C[M,N] = X[M,K] * Wt[N,K]^T + bias, K=N=1024, M=8192. bf16 MFMA, fp32 acc.
// BK=64. LDS chunk XOR-swizzle (slot s of row r holds global chunk s^(r&7));
// swizzle applied on the GLOBAL source (rule #21), global_load_lds dest linear.
// Grid (M/128, N/128), x=m-panel: linear ids = m (mod 8) -> XCD c owns
// m-panels = c (mod 8): per-XCD L2 footprint = 2MB A-rows + 2MB whole-B = 4MB
// (exact L2 fit). With x=n (r2) each XCD re-read ALL of A (8x L3 traffic).
// MODE 0: Y fp32 row-major [M,N];  MODE 1: bf16 [B,H,S,DK];  MODE 2: bf16
// [B,H,DK,S]. Block: 4 waves, tile 128x128, wave = 64x64 (4x4 MFMA).
// ---------------------------------------------------------------------------
template <int MODE, typename TX, typename TY>
__global__ __launch_bounds__(256) void gemm_bt(
    const TX* __restrict__ X, const bf16_t* __restrict__ Wt,
    const float* __restrict__ bias, TY* __restrict__ Y, float scale) {
    __shared__ __align__(16) bf16_t As[128 * 64];
    __shared__ __align__(16) bf16_t Bs[128 * 64];
    const int tid = threadIdx.x;
    const int lane = tid & 63, wave = tid >> 6;
    const int ln = lane & 15, quad = lane >> 4;
    const int wm = (wave & 1) * 64, wn = (wave >> 1) * 64;
    const int m0 = blockIdx.x * 128, n0 = blockIdx.y * 128;

    const int srow = tid >> 3;         // 0..31
    const int sch = tid & 7;           // LDS slot this thread fills
    const int swc = sch ^ (srow & 7);  // global chunk that belongs in slot sch

    const TX* pa = X + (size_t)(m0 + srow) * D_ + swc * 8;
    const bf16_t* pb = Wt + (size_t)(n0 + srow) * D_ + swc * 8;

    f32x4 acc[4][4] = {};
    for (int k0 = 0; k0 < D_; k0 += 64) {
        if constexpr (sizeof(TX) == 2) {
#pragma unroll
            for (int i = 0; i < 4; i++)
                gl_lds16(pa + (size_t)(i * 32) * D_ + k0,
                         As + i * 2048 + wave * 512);
        } else {
#pragma unroll
            for (int i = 0; i < 4; i++)
                *(bf16x8*)(As + (srow + i * 32) * 64 + sch * 8) =
                    load8(X + (size_t)(m0 + srow + i * 32) * D_ + k0 + swc * 8);
        }
#pragma unroll
        for (int i = 0; i < 4; i++)
            gl_lds16(pb + (size_t)(i * 32) * D_ + k0,
                     Bs + i * 2048 + wave * 512);
        __syncthreads();
#pragma unroll
        for (int kq = 0; kq < 2; kq++) {
            bf16x8 af[4], bfr[4];
            const int slot = ((kq * 4 + quad) ^ (ln & 7)) * 8;
#pragma unroll
            for (int mt = 0; mt < 4; mt++)
                af[mt] = *(const bf16x8*)(As + (wm + mt * 16 + ln) * 64 + slot);
#pragma unroll
            for (int nt = 0; nt < 4; nt++)
                bfr[nt] = *(const bf16x8*)(Bs + (wn + nt * 16 + ln) * 64 + slot);
#pragma unroll
            for (int mt = 0; mt < 4; mt++)
#pragma unroll
                for (int nt = 0; nt < 4; nt++)
                    acc[mt][nt] = mfma_bf16(af[mt], bfr[nt], acc[mt][nt]);
        }
        __syncthreads();
    }

#pragma unroll
    for (int mt = 0; mt < 4; mt++) {
#pragma unroll
        for (int nt = 0; nt < 4; nt++) {
#pragma unroll
            for (int r = 0; r < 4; r++) {
                const int m = m0 + wm + mt * 16 + quad * 4 + r;
                const int n = n0 + wn + nt * 16 + ln;
                const float v = (acc[mt][nt][r] + bias[n]) * scale;
                size_t idx;
                if (MODE == 0) {
                    idx = (size_t)m * D_ + n;
                } else {
                    const int b = m >> 10, s = m & 1023;
                    const int h = n >> 6, d = n & 63;
                    if (MODE == 1)
                        idx = ((size_t)(b * H_ + h) * S_ + s) * DK_ + d;
                    else
                        idx = ((size_t)(b * H_ + h) * DK_ + d) * S_ + s;
                }
                store_elem(Y, idx, v);
            }
        }
    }
}

// ---------------------------------------------------------------------------
// Causal flash attention, FIXED-max exp2-domain softmax.
// Q pre-scaled by log2e/sqrt(DK); p = exp2(score - 16), shift folded into the
// MFMA accumulator init. r2 showed direct-global K/V fragment loads are
// request-rate-limited (64 cache lines per 16B-stride-128B load; MfmaUtil 8%,
// HBM 7%). Fix: coalesced cooperative staging of K/V tiles into LDS via
// global_load_lds with PRE-SWIZZLED global source (rule #21): LDS dest stays
// linear, slot s of row r receives global chunk s^(r&7) -> ds_read_b128
// fragment reads are 2-way bank-conflict-free. Keeps r2's occupancy wins:
// grid (bh, chunk) = 1024 one-chunk blocks, launch_bounds(256,4) -> 4
// blocks/CU; barriers are per-block only (independent blocks hide them).
// pbuf (P transpose) is per-wave: intra-wave lgkmcnt ordering, no barrier.
// Row-sum via MFMA with a ones-fragment.
// Q,K: [B*H,S,DK]  Vt: [B*H,DK,S]  ctx: [B,S,D] bf16.
// ---------------------------------------------------------------------------
__global__ __launch_bounds__(256, 4) void MaskedMultiHeadAttention_90709709291709_kernel(
    const bf16_t* __restrict__ Q, const bf16_t* __restrict__ K,
    const bf16_t* __restrict__ Vt, bf16_t* __restrict__ ctx) {
    __shared__ __align__(16) bf16_t Ks[64 * 64];
    __shared__ __align__(16) bf16_t Vs[64 * 64];
    __shared__ __align__(16) bf16_t pbuf[4][32 * 64];

    const int bh = blockIdx.x;
    const int j = 7 - (int)blockIdx.y;  // heavy chunks dispatched first
    const int tid = threadIdx.x;
    const int lane = tid & 63, wave = tid >> 6;
    const int ln = lane & 15, quad = lane >> 4;

    const bf16_t* Qb = Q + (size_t)bh * S_ * DK_;
    const bf16_t* Kb = K + (size_t)bh * S_ * DK_;
    const bf16_t* Vb = Vt + (size_t)bh * DK_ * S_;
    const int b = bh >> 4, h = bh & 15;

    bf16x8 ones8;
#pragma unroll
    for (int i = 0; i < 8; i++) ones8[i] = (bf16_t)1.0f;

    const int qb = j * 128;
    const int wq = qb + wave * 32;
    bf16_t* pb = pbuf[wave];

    bf16x8 qf[2][2];
#pragma unroll
    for (int mi = 0; mi < 2; mi++)
#pragma unroll
        for (int kk = 0; kk < 2; kk++)
            qf[mi][kk] = *(const bf16x8*)(
                Qb + (size_t)(wq + mi * 16 + ln) * DK_ + kk * 32 + quad * 8);

    f32x4 o[2][4] = {};
    f32x4 ol[2] = {};

    // staging geometry: each gl_lds16 covers 8 rows x 64B; lane -> row group
    const int r8 = lane >> 3;              // row within 8-row group
    const int sc = (lane & 7) ^ r8;        // pre-swizzled source chunk

    const int kend = qb + 128;
    for (int kt = 0; kt < kend; kt += 64) {
        // -------- cooperative coalesced staging (4 gl_lds16 per thread) ----
#pragma unroll
        for (int i = 0; i < 2; i++) {
            const int row = (wave * 2 + i) * 8 + r8;
            gl_lds16(Kb + (size_t)(kt + row) * DK_ + sc * 8,
                     Ks + (wave * 2 + i) * 512);
            gl_lds16(Vb + (size_t)row * S_ + kt + sc * 8,
                     Vs + (wave * 2 + i) * 512);
        }
        __syncthreads();  // drains vmcnt (gl_lds) for the whole block

        if (kt <= wq + 31) {
            // -------- QK^T + masked exp2 -> pbuf (per-wave, swizzled) ------
#pragma unroll
            for (int nt = 0; nt < 4; nt++) {
                const bf16_t* kp = Ks + (nt * 16 + ln) * 64;
                const bf16x8 kf0 = *(const bf16x8*)(kp + ((quad ^ (ln & 7)) * 8));
                const bf16x8 kf1 =
                    *(const bf16x8*)(kp + (((4 + quad) ^ (ln & 7)) * 8));
#pragma unroll
                for (int mi = 0; mi < 2; mi++) {
                    f32x4 a = {-16.f, -16.f, -16.f, -16.f};  // exp2 shift
                    a = mfma_bf16(qf[mi][0], kf0, a);
                    a = mfma_bf16(qf[mi][1], kf1, a);
                    const bool needmask = (kt + 63) > (wq + mi * 16);
#pragma unroll
                    for (int r = 0; r < 4; r++) {
                        const int row = wq + mi * 16 + quad * 4 + r;
                        const int prow = mi * 16 + quad * 4 + r;
                        float v = a[r];
                        if (needmask && (kt + nt * 16 + ln > row)) v = NEGINF;
                        const float p = __builtin_amdgcn_exp2f(v);
                        const int col = nt * 16 + ln;
                        pb[prow * 64 + (((col >> 3) ^ (prow & 7)) * 8) +
                           (col & 7)] = (bf16_t)p;
                    }
                }
            }

            // -------- P * V (V fragments from LDS) -------------------------
            bf16x8 pf[2][2];
#pragma unroll
            for (int mi = 0; mi < 2; mi++)
#pragma unroll
                for (int kk = 0; kk < 2; kk++)
                    pf[mi][kk] = *(const bf16x8*)(
                        pb + (mi * 16 + ln) * 64 +
                        (((kk * 4 + quad) ^ (ln & 7)) * 8));
#pragma unroll
            for (int mi = 0; mi < 2; mi++) {
                ol[mi] = mfma_bf16(pf[mi][0], ones8, ol[mi]);
                ol[mi] = mfma_bf16(pf[mi][1], ones8, ol[mi]);
            }
#pragma unroll
            for (int dk = 0; dk < 4; dk++) {
                const bf16_t* vp = Vs + (dk * 16 + ln) * 64;
                const bf16x8 vf0 = *(const bf16x8*)(vp + ((quad ^ (ln & 7)) * 8));
                const bf16x8 vf1 =
                    *(const bf16x8*)(vp + (((4 + quad) ^ (ln & 7)) * 8));
#pragma unroll
                for (int mi = 0; mi < 2; mi++) {
                    o[mi][dk] = mfma_bf16(pf[mi][0], vf0, o[mi][dk]);
                    o[mi][dk] = mfma_bf16(pf[mi][1], vf1, o[mi][dk]);
                }
            }
        }
        __syncthreads();  // all reads of Ks/Vs done before next staging
    }

#pragma unroll
    for (int mi = 0; mi < 2; mi++)
#pragma unroll
        for (int r = 0; r < 4; r++) {
            const float inv = 1.f / ol[mi][r];
            const int row = wq + mi * 16 + quad * 4 + r;
            const size_t base = ((size_t)b * S_ + row) * D_ + h * DK_;
#pragma unroll
            for (int dk = 0; dk < 4; dk++)
                ctx[base + dk * 16 + ln] = (bf16_t)(o[mi][dk][r] * inv);
        }
}

// Vectorized d2d copy (16B per thread).
__global__ __launch_bounds__(256) void copy16(const f32x4* __restrict__ src,
                                              f32x4* __restrict__ dst, int n4) {
    const int i = blockIdx.x * 256 + threadIdx.x;
    if (i < n4) dst[i] = src[i];
}

extern "C" void kernel_launch(void* const* d_in, const int* in_sizes, int n_in,
                              void* d_out, int out_size, void* d_ws,
                              size_t ws_size, hipStream_t stream) {
    const float* query = (const float*)d_in[0];
    const float* key = (const float*)d_in[1];
    const float* value = (const float*)d_in[2];
    const float* w_q = (const float*)d_in[4];
    const float* b_q = (const float*)d_in[5];
    const float* w_k = (const float*)d_in[6];
    const float* b_k = (const float*)d_in[7];
    const float* w_v = (const float*)d_in[8];
    const float* b_v = (const float*)d_in[9];
    const float* w_o = (const float*)d_in[10];
    const float* b_o = (const float*)d_in[11];

    bf16_t* ws = (bf16_t*)d_ws;
    const size_t M8 = (size_t)M_ * D_;  // 8M elems
    bf16_t* Qw = ws;                    // [0, 8M)
    bf16_t* Kw = ws + M8;               // [8M, 16M)
    bf16_t* Vw = ws + 2 * M8;           // [16M, 24M)
    bf16_t* wtq = ws + 3 * M8;          // [24M, 28M): 4 x 1M
    bf16_t* wtk = wtq + (size_t)D_ * D_;
    bf16_t* wtv = wtk + (size_t)D_ * D_;
    bf16_t* wto = wtv + (size_t)D_ * D_;

    // bf16 X scratch parks in d_out's first 16 MB: d_out is not needed as
    // ctx (!direct) or final out (direct) until AFTER the last cvt consumer.
    bf16_t* Xb = (bf16_t*)d_out;

    // If ws is big enough (>= 72 MB), park ctx in ws and write the final
    // fp32 output GEMM directly into d_out -> no copy pass. Otherwise fall
    // back to the ctx-in-d_out + copy scheme (56 MB footprint).
    const size_t need_direct = (4 * M8 + 4 * (size_t)D_ * D_) * sizeof(bf16_t);
    const bool direct = ws_size >= need_direct;
    bf16_t* Cw = direct ? (ws + 3 * M8 + 4 * (size_t)D_ * D_)
                        : (bf16_t*)d_out;
    float* Yw = direct ? (float*)d_out : (float*)ws;

    transpose4<<<dim3(32, 32, 4), dim3(32, 8, 1), 0, stream>>>(
        w_q, w_k, w_v, w_o, wtq, wtk, wtv, wto);

    const dim3 gg(M_ / 128, D_ / 128, 1);  // x=m-panel -> XCD owns 1/8 of A
    const int n8 = (int)(M8 / 8);
    const dim3 gc((n8 + 255) / 256, 1, 1);
    // Q scale folds 1/sqrt(DK) AND log2(e) for the exp2-domain softmax.
    const float qscale = 0.125f * 1.4426950408889634f;

    cvt_bf16<<<gc, 256, 0, stream>>>(query, Xb, n8);
    gemm_bt<1><<<gg, 256, 0, stream>>>(Xb, wtq, b_q, Qw, qscale);
    cvt_bf16<<<gc, 256, 0, stream>>>(key, Xb, n8);
    gemm_bt<1><<<gg, 256, 0, stream>>>(Xb, wtk, b_k, Kw, 1.0f);
    cvt_bf16<<<gc, 256, 0, stream>>>(value, Xb, n8);
    gemm_bt<2><<<gg, 256, 0, stream>>>(Xb, wtv, b_v, Vw, 1.0f);

    MaskedMultiHeadAttention_90709709291709_kernel<<<dim3(B_ * H_, 8, 1), 256,
                                                     0, stream>>>(Qw, Kw, Vw,
                                                                  Cw);

    gemm_bt<0><<<gg, 256, 0, stream>>>(Cw, wto, b_o, Yw, 1.0f);
    if (!direct) {
        const int n4 = (int)((M8 * 4) / 16);
        copy16<<<dim3((n4 + 255) / 256), 256, 0, stream>>>((const f32x4*)Yw,
                                                           (f32x4*)d_out, n4);
    }
}

// Round 4
// 309.711 us; speedup vs baseline: 1.6275x; 1.0589x over previous
//
#include <hip/hip_runtime.h>

#define B_ 8
#define S_ 1024
#define D_ 1024
#define H_ 16
#define DK_ 64
#define M_ (B_ * S_)
#define NEGINF -1e38f

typedef __bf16 bf16_t;
typedef __bf16 bf16x8 __attribute__((ext_vector_type(8)));
typedef float f32x4 __attribute__((ext_vector_type(4)));
typedef unsigned int u32;

__device__ inline f32x4 mfma_bf16(bf16x8 a, bf16x8 b, f32x4 c) {
    return __builtin_amdgcn_mfma_f32_16x16x32_bf16(a, b, c, 0, 0, 0);
}

// Async global->LDS, 16B per lane. LDS dest = (wave-uniform base) + lane*16B.
typedef const __attribute__((address_space(1))) u32* gas1_t;
typedef __attribute__((address_space(3))) u32* las3_t;
__device__ inline void gl_lds16(const void* g, void* l) {
    __builtin_amdgcn_global_load_lds((gas1_t)g, (las3_t)l, 16, 0, 0);
}

// 8 contiguous elements -> bf16x8 (converting when source is fp32).
__device__ inline bf16x8 load8(const bf16_t* p) { return *(const bf16x8*)p; }
__device__ inline bf16x8 load8(const float* p) {
    const f32x4 a = *(const f32x4*)p;
    const f32x4 b = *(const f32x4*)(p + 4);
    bf16x8 r;
    r[0] = (bf16_t)a[0]; r[1] = (bf16_t)a[1];
    r[2] = (bf16_t)a[2]; r[3] = (bf16_t)a[3];
    r[4] = (bf16_t)b[0]; r[5] = (bf16_t)b[1];
    r[6] = (bf16_t)b[2]; r[7] = (bf16_t)b[3];
    return r;
}
__device__ inline void store_elem(bf16_t* Y, size_t i, float v) { Y[i] = (bf16_t)v; }
__device__ inline void store_elem(float* Y, size_t i, float v) { Y[i] = v; }

// ---------------------------------------------------------------------------
// Transpose+convert 4 fp32 weight matrices [1024,1024] -> bf16 transposed.
// ---------------------------------------------------------------------------
__global__ __launch_bounds__(256) void transpose4(
    const float* __restrict__ i0, const float* __restrict__ i1,
    const float* __restrict__ i2, const float* __restrict__ i3,
    bf16_t* __restrict__ o0, bf16_t* __restrict__ o1,
    bf16_t* __restrict__ o2, bf16_t* __restrict__ o3) {
    const float* ins[4] = {i0, i1, i2, i3};
    bf16_t* outs[4] = {o0, o1, o2, o3};
    const float* in = ins[blockIdx.z];
    bf16_t* out = outs[blockIdx.z];
    __shared__ __align__(16) bf16_t t[32][33];
    const int n0 = blockIdx.x * 32, k0 = blockIdx.y * 32;
    const int tx = threadIdx.x;
    for (int i = threadIdx.y; i < 32; i += 8)
        t[i][tx] = (bf16_t)in[(size_t)(k0 + i) * D_ + n0 + tx];
    __syncthreads();
    for (int i = threadIdx.y; i < 32; i += 8)
        out[(size_t)(n0 + i) * D_ + k0 + tx] = t[tx][i];
}

// fp32 -> bf16 bulk convert, 8 elems/thread (16B loads, 16B stores).
__global__ __launch_bounds__(256) void cvt_bf16(const float* __restrict__ in,
                                                bf16_t* __restrict__ out,
                                                int n8) {
    const int i = blockIdx.x * 256 + threadIdx.x;
    if (i < n8) *(bf16x8*)(out + (size_t)i * 8) = load8(in + (size_t)i * 8);
}

// ---------------------------------------------------------------------------
// C[M,N] = X[M,K] * Wt[N,K]^T + bias, K=N=1024, M=8192. bf16 MFMA, fp32 acc.
// 2-PHASE double-buffered pipeline (catalog T3-minimum): per K-iter, issue
// next tile's global_load_lds FIRST, then ds_read+MFMA current, then ONE
// __syncthreads() (vmcnt(0)+lgkmcnt(0)+barrier): the stage's HBM/L2 latency
// hides under this iter's 32 MFMAs. LDS 64KB = 2 blocks/CU = resident grid.
// LDS chunk XOR-swizzle (slot s of row r holds chunk s^(r&7)) applied on the
// GLOBAL source (rule #21); gl_lds dest linear; ds_read_b128 conflict-free.
// Grid (M/128, N/128): x=m-panel -> XCD owns 1/8 of A + whole B = 4MB L2 fit.
// ---------------------------------------------------------------------------
template <int MODE, typename TX, typename TY>
__global__ __launch_bounds__(256) void gemm_bt(
    const TX* __restrict__ X, const bf16_t* __restrict__ Wt,
    const float* __restrict__ bias, TY* __restrict__ Y, float scale) {
    __shared__ __align__(16) bf16_t As[2][128 * 64];
    __shared__ __align__(16) bf16_t Bs[2][128 * 64];
    const int tid = threadIdx.x;
    const int lane = tid & 63, wave = tid >> 6;
    const int ln = lane & 15, quad = lane >> 4;
    const int wm = (wave & 1) * 64, wn = (wave >> 1) * 64;
    const int m0 = blockIdx.x * 128, n0 = blockIdx.y * 128;

    const int srow = tid >> 3;         // 0..31
    const int sch = tid & 7;           // LDS slot this thread fills
    const int swc = sch ^ (srow & 7);  // global chunk that belongs in slot sch

    const TX* pa = X + (size_t)(m0 + srow) * D_ + swc * 8;
    const bf16_t* pb = Wt + (size_t)(n0 + srow) * D_ + swc * 8;

    auto stage = [&](int d, int k0) {
        if constexpr (sizeof(TX) == 2) {
#pragma unroll
            for (int i = 0; i < 4; i++)
                gl_lds16(pa + (size_t)(i * 32) * D_ + k0,
                         As[d] + i * 2048 + wave * 512);
        } else {
#pragma unroll
            for (int i = 0; i < 4; i++)
                *(bf16x8*)(As[d] + (srow + i * 32) * 64 + sch * 8) =
                    load8(X + (size_t)(m0 + srow + i * 32) * D_ + k0 + swc * 8);
        }
#pragma unroll
        for (int i = 0; i < 4; i++)
            gl_lds16(pb + (size_t)(i * 32) * D_ + k0,
                     Bs[d] + i * 2048 + wave * 512);
    };

    stage(0, 0);
    __syncthreads();

    f32x4 acc[4][4] = {};
    int cur = 0;
    for (int t = 0; t < 16; ++t) {
        if (t < 15) stage(cur ^ 1, (t + 1) * 64);  // async, drains at barrier
#pragma unroll
        for (int kq = 0; kq < 2; kq++) {
            bf16x8 af[4], bfr[4];
            const int slot = ((kq * 4 + quad) ^ (ln & 7)) * 8;
#pragma unroll
            for (int mt = 0; mt < 4; mt++)
                af[mt] =
                    *(const bf16x8*)(As[cur] + (wm + mt * 16 + ln) * 64 + slot);
#pragma unroll
            for (int nt = 0; nt < 4; nt++)
                bfr[nt] =
                    *(const bf16x8*)(Bs[cur] + (wn + nt * 16 + ln) * 64 + slot);
#pragma unroll
            for (int mt = 0; mt < 4; mt++)
#pragma unroll
                for (int nt = 0; nt < 4; nt++)
                    acc[mt][nt] = mfma_bf16(af[mt], bfr[nt], acc[mt][nt]);
        }
        __syncthreads();  // vmcnt(0)+lgkmcnt(0)+barrier: next buf ready
        cur ^= 1;
    }

#pragma unroll
    for (int mt = 0; mt < 4; mt++) {
#pragma unroll
        for (int nt = 0; nt < 4; nt++) {
#pragma unroll
            for (int r = 0; r < 4; r++) {
                const int m = m0 + wm + mt * 16 + quad * 4 + r;
                const int n = n0 + wn + nt * 16 + ln;
                const float v = (acc[mt][nt][r] + bias[n]) * scale;
                size_t idx;
                if (MODE == 0) {
                    idx = (size_t)m * D_ + n;
                } else {
                    const int b = m >> 10, s = m & 1023;
                    const int h = n >> 6, d = n & 63;
                    if (MODE == 1)
                        idx = ((size_t)(b * H_ + h) * S_ + s) * DK_ + d;
                    else
                        idx = ((size_t)(b * H_ + h) * DK_ + d) * S_ + s;
                }
                store_elem(Y, idx, v);
            }
        }
    }
}

// ---------------------------------------------------------------------------
// Causal flash attention, FIXED-max exp2-domain softmax, P IN REGISTERS.
// Swapped-operand QK^T: S^T = mfma(A=K_frag, B=Q_frag) puts the whole P-row
// for q = wq+mi*16+ln in lane ln's registers. K rows are PERMUTED at staging
// (bit-shuffle applied to the per-lane GLOBAL source row; LDS dest linear,
// rule #21) so that S^T output positions coincide exactly with the PV
// A-fragment layout: position p=nt*16+quad*4+r holds true k with bits
// k5..k0 = p4,p3,p2,p5,p1,p0, i.e. k = (nt&1)*32 + quad*8 + (nt>>1)*4 + r.
// The P->PV repack is then a pure in-register bf16 cast (no pbuf LDS, no
// cross-lane ops): removes 32 ds_write_u16 + 4 ds_read_b128 per thread/tile.
// Rowsum via MFMA with ones (order-independent, permutation-safe). V staging
// and PV B-fragments unchanged; output C/D mapping unchanged -> epilogue
// identical. exp2-domain shift (-16) folded into QK accumulator init.
// Grid (bh, chunk): same-bh blocks -> same XCD (K/V L2-resident);
// launch_bounds(256,4): 4 blocks/CU. LDS 16KB (Ks+Vs only).
// Q,K: [B*H,S,DK]  Vt: [B*H,DK,S]  ctx: [B,S,D] bf16.
// ---------------------------------------------------------------------------
__global__ __launch_bounds__(256, 4) void MaskedMultiHeadAttention_90709709291709_kernel(
    const bf16_t* __restrict__ Q, const bf16_t* __restrict__ K,
    const bf16_t* __restrict__ Vt, bf16_t* __restrict__ ctx) {
    __shared__ __align__(16) bf16_t Ks[64 * 64];
    __shared__ __align__(16) bf16_t Vs[64 * 64];

    const int bh = blockIdx.x;
    const int j = 7 - (int)blockIdx.y;  // heavy chunks dispatched first
    const int tid = threadIdx.x;
    const int lane = tid & 63, wave = tid >> 6;
    const int ln = lane & 15, quad = lane >> 4;

    const bf16_t* Qb = Q + (size_t)bh * S_ * DK_;
    const bf16_t* Kb = K + (size_t)bh * S_ * DK_;
    const bf16_t* Vb = Vt + (size_t)bh * DK_ * S_;
    const int b = bh >> 4, h = bh & 15;

    bf16x8 ones8;
#pragma unroll
    for (int i = 0; i < 8; i++) ones8[i] = (bf16_t)1.0f;

    const int qb = j * 128;
    const int wq = qb + wave * 32;

    bf16x8 qf[2][2];
#pragma unroll
    for (int mi = 0; mi < 2; mi++)
#pragma unroll
        for (int kk = 0; kk < 2; kk++)
            qf[mi][kk] = *(const bf16x8*)(
                Qb + (size_t)(wq + mi * 16 + ln) * DK_ + kk * 32 + quad * 8);

    f32x4 o[2][4] = {};
    f32x4 ol[2] = {};

    // staging geometry: each gl_lds16 covers 8 rows x 64B
    const int r8 = lane >> 3;        // row-in-group 0..7
    const int sc = (lane & 7) ^ r8;  // pre-swizzled source chunk (key = row&7)

    const int kend = qb + 128;
    for (int kt = 0; kt < kend; kt += 64) {
        // ---- cooperative staging; K rows bit-shuffle-permuted at source ----
#pragma unroll
        for (int i = 0; i < 2; i++) {
            const int g = wave * 2 + i;  // 8-row group 0..7
            // LDS position p = g*8+r8 receives K row k(p):
            // k = g1*32 + g0*16 + r8_2*8 + g2*4 + (r8&3)
            const int krow = (g & 2) * 16 + (g & 1) * 16 + (r8 & 4) * 2 +
                             (g & 4) + (r8 & 3);
            gl_lds16(Kb + (size_t)(kt + krow) * DK_ + sc * 8, Ks + g * 512);
            gl_lds16(Vb + (size_t)(g * 8 + r8) * S_ + kt + sc * 8,
                     Vs + g * 512);
        }
        __syncthreads();

        if (kt <= wq + 31) {
            bf16x8 pa[2][2];  // [mi][kk] PV A-fragments, built in-register
#pragma unroll
            for (int mi = 0; mi < 2; mi++) {
                f32x4 s[4];
#pragma unroll
                for (int nt = 0; nt < 4; nt++) {
                    const bf16_t* kp = Ks + (nt * 16 + ln) * 64;
                    const bf16x8 kf0 =
                        *(const bf16x8*)(kp + ((quad ^ (ln & 7)) * 8));
                    const bf16x8 kf1 =
                        *(const bf16x8*)(kp + (((4 + quad) ^ (ln & 7)) * 8));
                    f32x4 a = {-16.f, -16.f, -16.f, -16.f};  // exp2 shift
                    a = mfma_bf16(kf0, qf[mi][0], a);  // swapped operands
                    a = mfma_bf16(kf1, qf[mi][1], a);
                    s[nt] = a;
                }
                const int q = wq + mi * 16 + ln;  // lane's q-row (global)
                const bool needmask = (kt + 63) > q;
#pragma unroll
                for (int nt = 0; nt < 4; nt++)
#pragma unroll
                    for (int r = 0; r < 4; r++) {
                        const int ktrue = kt + (nt & 1) * 32 + quad * 8 +
                                          (nt >> 1) * 4 + r;
                        float v = s[nt][r];
                        if (needmask && ktrue > q) v = NEGINF;
                        s[nt][r] = __builtin_amdgcn_exp2f(v);
                    }
                // pack: pa[kk] elem j=2w+e <- s[2*(w>>1)+kk][2*(w&1)+e]
#pragma unroll
                for (int kk = 0; kk < 2; kk++) {
                    bf16x8 t;
#pragma unroll
                    for (int w = 0; w < 4; w++) {
                        const int nts = 2 * (w >> 1) + kk;
                        const int r0 = 2 * (w & 1);
                        t[2 * w] = (bf16_t)s[nts][r0];
                        t[2 * w + 1] = (bf16_t)s[nts][r0 + 1];
                    }
                    pa[mi][kk] = t;
                }
                ol[mi] = mfma_bf16(pa[mi][0], ones8, ol[mi]);
                ol[mi] = mfma_bf16(pa[mi][1], ones8, ol[mi]);
            }
            // ---- P * V (V fragments from LDS, shared across mi) ----
#pragma unroll
            for (int dk = 0; dk < 4; dk++) {
                const bf16_t* vp = Vs + (dk * 16 + ln) * 64;
                const bf16x8 vf0 = *(const bf16x8*)(vp + ((quad ^ (ln & 7)) * 8));
                const bf16x8 vf1 =
                    *(const bf16x8*)(vp + (((4 + quad) ^ (ln & 7)) * 8));
#pragma unroll
                for (int mi = 0; mi < 2; mi++) {
                    o[mi][dk] = mfma_bf16(pa[mi][0], vf0, o[mi][dk]);
                    o[mi][dk] = mfma_bf16(pa[mi][1], vf1, o[mi][dk]);
                }
            }
        }
        __syncthreads();  // Ks/Vs reads done before next staging pass
    }

#pragma unroll
    for (int mi = 0; mi < 2; mi++)
#pragma unroll
        for (int r = 0; r < 4; r++) {
            const float inv = 1.f / ol[mi][r];
            const int row = wq + mi * 16 + quad * 4 + r;
            const size_t base = ((size_t)b * S_ + row) * D_ + h * DK_;
#pragma unroll
            for (int dk = 0; dk < 4; dk++)
                ctx[base + dk * 16 + ln] = (bf16_t)(o[mi][dk][r] * inv);
        }
}

// Vectorized d2d copy (16B per thread).
__global__ __launch_bounds__(256) void copy16(const f32x4* __restrict__ src,
                                              f32x4* __restrict__ dst, int n4) {
    const int i = blockIdx.x * 256 + threadIdx.x;
    if (i < n4) dst[i] = src[i];
}

extern "C" void kernel_launch(void* const* d_in, const int* in_sizes, int n_in,
                              void* d_out, int out_size, void* d_ws,
                              size_t ws_size, hipStream_t stream) {
    const float* query = (const float*)d_in[0];
    const float* key = (const float*)d_in[1];
    const float* value = (const float*)d_in[2];
    const float* w_q = (const float*)d_in[4];
    const float* b_q = (const float*)d_in[5];
    const float* w_k = (const float*)d_in[6];
    const float* b_k = (const float*)d_in[7];
    const float* w_v = (const float*)d_in[8];
    const float* b_v = (const float*)d_in[9];
    const float* w_o = (const float*)d_in[10];
    const float* b_o = (const float*)d_in[11];

    bf16_t* ws = (bf16_t*)d_ws;
    const size_t M8 = (size_t)M_ * D_;  // 8M elems
    bf16_t* Qw = ws;                    // [0, 8M)
    bf16_t* Kw = ws + M8;               // [8M, 16M)
    bf16_t* Vw = ws + 2 * M8;           // [16M, 24M)
    bf16_t* wtq = ws + 3 * M8;          // [24M, 28M): 4 x 1M
    bf16_t* wtk = wtq + (size_t)D_ * D_;
    bf16_t* wtv = wtk + (size_t)D_ * D_;
    bf16_t* wto = wtv + (size_t)D_ * D_;

    // bf16 X scratch parks in d_out's first 16 MB: d_out is not needed as
    // ctx (!direct) or final out (direct) until AFTER the last cvt consumer.
    bf16_t* Xb = (bf16_t*)d_out;

    // If ws is big enough (>= 72 MB), park ctx in ws and write the final
    // fp32 output GEMM directly into d_out -> no copy pass. Otherwise fall
    // back to the ctx-in-d_out + copy scheme (56 MB footprint).
    const size_t need_direct = (4 * M8 + 4 * (size_t)D_ * D_) * sizeof(bf16_t);
    const bool direct = ws_size >= need_direct;
    bf16_t* Cw = direct ? (ws + 3 * M8 + 4 * (size_t)D_ * D_)
                        : (bf16_t*)d_out;
    float* Yw = direct ? (float*)d_out : (float*)ws;

    transpose4<<<dim3(32, 32, 4), dim3(32, 8, 1), 0, stream>>>(
        w_q, w_k, w_v, w_o, wtq, wtk, wtv, wto);

    const dim3 gg(M_ / 128, D_ / 128, 1);  // x=m-panel -> XCD owns 1/8 of A
    const int n8 = (int)(M8 / 8);
    const dim3 gc((n8 + 255) / 256, 1, 1);
    // Q scale folds 1/sqrt(DK) AND log2(e) for the exp2-domain softmax.
    const float qscale = 0.125f * 1.4426950408889634f;

    cvt_bf16<<<gc, 256, 0, stream>>>(query, Xb, n8);
    gemm_bt<1><<<gg, 256, 0, stream>>>(Xb, wtq, b_q, Qw, qscale);
    cvt_bf16<<<gc, 256, 0, stream>>>(key, Xb, n8);
    gemm_bt<1><<<gg, 256, 0, stream>>>(Xb, wtk, b_k, Kw, 1.0f);
    cvt_bf16<<<gc, 256, 0, stream>>>(value, Xb, n8);
    gemm_bt<2><<<gg, 256, 0, stream>>>(Xb, wtv, b_v, Vw, 1.0f);

    MaskedMultiHeadAttention_90709709291709_kernel<<<dim3(B_ * H_, 8, 1), 256,
                                                     0, stream>>>(Qw, Kw, Vw,
                                                                  Cw);

    gemm_bt<0><<<gg, 256, 0, stream>>>(Cw, wto, b_o, Yw, 1.0f);
    if (!direct) {
        const int n4 = (int)((M8 * 4) / 16);
        copy16<<<dim3((n4 + 255) / 256), 256, 0, stream>>>((const f32x4*)Yw,
                                                           (f32x4*)d_out, n4);
    }
}